// Round 15
// baseline (1041.557 us; speedup 1.0000x reference)
//
#include <hip/hip_runtime.h>
#include <stdint.h>

// Problem constants
#define B_    64
#define L_    512
#define EMB_  128
#define HID_  256
#define OUT_  32

typedef float    f32x4  __attribute__((ext_vector_type(4)));
typedef _Float16 f16x4v __attribute__((ext_vector_type(4)));
typedef _Float16 f16x8v __attribute__((ext_vector_type(8)));

#define MFMA(a,b,c) __builtin_amdgcn_mfma_f32_16x16x32_f16((a),(b),(c),0,0,0)
#define POISON 0xFFFFFFFFFFFFFFFFull

__device__ __forceinline__ f16x4v cvt4(const float4 v){
  f16x4v r = {(_Float16)v.x,(_Float16)v.y,(_Float16)v.z,(_Float16)v.w};
  return r;
}

union u64f16 { unsigned long long u[2]; f16x8v v; };

// MFMA 16x16x32 fragment convention used throughout (lane = 16*g + r):
//   A[16m x 32k]: row = r, k = kt*32 + (j<4 ? 4g+j : 16+4g+(j-4))
//   B[32k x 16n]: col = r, same k mapping
//   D f32x4:      row(m) = 4g+reg, col(n) = r            [m89 HW-verified]

// ---------------- Phase 1: Wx[dir][l][row(1024)][b(64)] f16 = x@Wih^T + bih + bhh
// v2 (proven round 11/12): 1024 blocks; Wih slice staged into LDS ONCE;
// bias hoisted; 8-l loop with two barriers per iteration.
__global__ __launch_bounds__(256) void k_wx(
    const int* __restrict__ sents, const float* __restrict__ emb,
    const float* __restrict__ WihF, const float* __restrict__ WihB,
    const float* __restrict__ bihF, const float* __restrict__ bhhF,
    const float* __restrict__ bihB, const float* __restrict__ bhhB,
    _Float16* __restrict__ wx)
{
  __shared__ _Float16 Af[4*4*64*8];   // 16 KB  x-tile fragments [mt][kt][lane][8]
  __shared__ _Float16 Bf[8*4*64*8];   // 32 KB  Wih fragments [nt][kt][lane][8]
  __shared__ _Float16 Tt[128*64];     // 16 KB  [col][b] out tile
  const int bid = blockIdx.x;         // 0..1023
  const int lb  = (bid >> 4) * 8;     // base l of this block's 8-l chunk
  const int ntb = bid & 15;
  const int dir = ntb >> 3;
  const int tid = threadIdx.x;

  const float* Wih = dir ? WihB : WihF;
  for (int it = 0; it < 16; ++it) {
    int cid = it*256 + tid;               // 4096 = 128 cols * 32 quad-chunks
    int c = cid >> 5, ec = cid & 31, e0 = ec*4;
    int rl = (ntb&7)*128 + c;
    float4 v = *(const float4*)(Wih + (size_t)rl*EMB_ + e0);
    int g = ec & 3, hi = (ec>>2)&1, kt = ec>>3;
    int lane = g*16 + (c&15), nt = c>>4;
    *(f16x4v*)&Bf[(((nt*4+kt)*64 + lane)<<3) + hi*4] = cvt4(v);
  }

  const int w = tid>>6, l64 = tid&63, gq = l64>>4, r = l64&15;
  const float* bih = dir ? bihB : bihF;
  const float* bhh = dir ? bhhB : bhhF;
  float bias8[8];
  #pragma unroll
  for (int nt = 0; nt < 8; ++nt) {
    int rl = (ntb&7)*128 + nt*16 + r;
    bias8[nt] = bih[rl] + bhh[rl];
  }

  for (int li = 0; li < 8; ++li) {
    const int l = lb + li;
    for (int it = 0; it < 8; ++it) {
      int cid = it*256 + tid;             // 2048 = 64 b * 32 quad-chunks
      int b = cid >> 5, ec = cid & 31, e0 = ec*4;
      int tok = sents[b*L_ + l];
      float4 v = *(const float4*)(emb + (size_t)tok*EMB_ + e0);
      int g = ec & 3, hi = (ec>>2)&1, kt = ec>>3;
      int lane = g*16 + (b&15), mt = b>>4;
      *(f16x4v*)&Af[(((mt*4+kt)*64 + lane)<<3) + hi*4] = cvt4(v);
    }
    __syncthreads();                      // Af (and, on li=0, Bf) ready

    #pragma unroll
    for (int nt = 0; nt < 8; ++nt) {
      f32x4 acc = {0.f,0.f,0.f,0.f};
      #pragma unroll
      for (int kt = 0; kt < 4; ++kt) {
        f16x8v a = *(f16x8v*)&Af[((w*4+kt)*64 + l64)<<3];
        f16x8v b = *(f16x8v*)&Bf[((nt*4+kt)*64 + l64)<<3];
        acc = MFMA(a,b,acc);
      }
      int col = nt*16 + r;
      float bias = bias8[nt];
      f16x4v o4 = {(_Float16)(acc[0]+bias),(_Float16)(acc[1]+bias),
                   (_Float16)(acc[2]+bias),(_Float16)(acc[3]+bias)};
      *(f16x4v*)&Tt[col*64 + w*16 + gq*4] = o4;
    }
    __syncthreads();                      // Tt complete; Af reads done

    _Float16* gdst = wx + ((size_t)(dir*L_ + l)*1024 + (size_t)(ntb&7)*128)*64;
    for (int q = 0; q < 4; ++q) {
      int idx = tid*32 + q*8;
      *(f16x8v*)(gdst + idx) = *(f16x8v*)&Tt[idx];
    }
  }
}

// ---------------- Phase 2: LSTM scan (round-12 protocol: per-u64 poison,
// ds_read_b64 wave-local publish, relaxed barrier). Round-14 proved the
// 2-way split consume (+37us); this extends it to 4-WAY: each u64-pair
// check's counted vmcnt leaves the later loads in flight, and each 4-MFMA
// cluster covers the next pair's residual RT. Only f0's RT stays exposed.
__global__ __launch_bounds__(512, 2) void k_scan(
    const float* __restrict__ WhhF, const float* __restrict__ WhhB,
    const _Float16* __restrict__ wx, _Float16* __restrict__ mb)
{
  __shared__ _Float16 hA[2][2048];    // ping-pong OWN-half h A-frags [ktl 4][lane 64][8]
  const int bid  = blockIdx.x;
  const int dir  = bid >> 3;
  const int bgrp = (bid >> 1) & 3;
  const int half = bid & 1;
  const int tid  = threadIdx.x;
  const int w    = tid >> 6;          // wave 0..7 -> unit group ug = half*8+w
  const int lane = tid & 63;
  const int gq   = lane >> 4;
  const int r    = lane & 15;
  const int u    = (half*8 + w)*16 + r;

  // ---- Whh B-fragments into registers (half-relative k): 128 VGPRs
  const float* Whh = dir ? WhhB : WhhF;
  f16x8v wf[4][8];
  #pragma unroll
  for (int nt = 0; nt < 4; ++nt) {
    #pragma unroll
    for (int kk = 0; kk < 8; ++kk) {
      int ktg = (kk < 4) ? (half*4 + kk) : ((half^1)*4 + (kk - 4));
      const float* src = Whh + (size_t)(nt*HID_ + u)*HID_ + ktg*32 + gq*4;
      float4 v1 = *(const float4*)(src);
      float4 v2 = *(const float4*)(src + 16);
      f16x8v p = {(_Float16)v1.x,(_Float16)v1.y,(_Float16)v1.z,(_Float16)v1.w,
                  (_Float16)v2.x,(_Float16)v2.y,(_Float16)v2.z,(_Float16)v2.w};
      wf[nt][kk] = p;
    }
  }

  // ---- zero own-half h0 fragments
  {
    f16x8v z = {(_Float16)0,(_Float16)0,(_Float16)0,(_Float16)0,
                (_Float16)0,(_Float16)0,(_Float16)0,(_Float16)0};
    if (tid < 256) *(f16x8v*)&hA[0][tid*8] = z;
  }

  // ---- Wx addressing: row = g*256 + u, batch offset = bgrp*16 + gq*4
  const _Float16* wxd = wx + (size_t)dir * 33554432ull;   // 512*1024*64
  const size_t woff = (size_t)u*64 + bgrp*16 + gq*4;
  // ---- scatter constants (own new-h into LOCAL A-fragment layout)
  const int ktl   = w >> 1;
  const int sbase = (ktl*64 + (r>>2)*16 + gq*4)*8 + (w&1)*4 + (r&3);
  // ---- publish word: u64 index (own half) whose 4 f16 are written by MY wave
  const int pword = ((w>>1)*64 + lane)*2 + (w&1);   // 0..511
  const int plds  = pword*4;                        // f16 index into hA[nb]
  // ---- mailbox: slot(dir,pos,bgrp) = 1024 u64; own half = 512 u64
  unsigned long long* mbu = (unsigned long long*)mb;
  const size_t slotb = ((size_t)dir*512*4 + bgrp);  // *1024 u64 later
  const int phalf = half ^ 1;

  float c0=0.f, c1=0.f, c2=0.f, c3=0.f;
  f16x4v xc0,xc1,xc2,xc3, xn0,xn1,xn2,xn3;
  {
    const int p0 = dir ? 511 : 0;
    const int p1 = dir ? 510 : 1;
    const _Float16* a = wxd + (size_t)p0*65536 + woff;
    const _Float16* b = wxd + (size_t)p1*65536 + woff;
    xc0 = *(const f16x4v*)(a + 0*16384); xc1 = *(const f16x4v*)(a + 1*16384);
    xc2 = *(const f16x4v*)(a + 2*16384); xc3 = *(const f16x4v*)(a + 3*16384);
    xn0 = *(const f16x4v*)(b + 0*16384); xn1 = *(const f16x4v*)(b + 1*16384);
    xn2 = *(const f16x4v*)(b + 2*16384); xn3 = *(const f16x4v*)(b + 3*16384);
  }
  __syncthreads();

  for (int t = 0; t < L_; ++t) {
    const int cur = t & 1, nb = cur ^ 1;
    const int pos = dir ? (511 - t) : t;

    // ---- issue partner poll loads FIRST (RT overlaps ownGEMM below)
    const int ppos = dir ? (512 - t) : (t - 1);
    const unsigned long long* pb =
        mbu + ((slotb + (size_t)ppos*4)<<10) + (phalf<<9);
    const unsigned long long* q0 = pb + ((0*64 + lane)<<1);
    const unsigned long long* q1 = pb + ((1*64 + lane)<<1);
    const unsigned long long* q2 = pb + ((2*64 + lane)<<1);
    const unsigned long long* q3 = pb + ((3*64 + lane)<<1);
    u64f16 f0, f1, f2, f3;
    if (t > 0) {
      f0.u[0] = __hip_atomic_load(q0,   __ATOMIC_RELAXED, __HIP_MEMORY_SCOPE_AGENT);
      f0.u[1] = __hip_atomic_load(q0+1, __ATOMIC_RELAXED, __HIP_MEMORY_SCOPE_AGENT);
      f1.u[0] = __hip_atomic_load(q1,   __ATOMIC_RELAXED, __HIP_MEMORY_SCOPE_AGENT);
      f1.u[1] = __hip_atomic_load(q1+1, __ATOMIC_RELAXED, __HIP_MEMORY_SCOPE_AGENT);
      f2.u[0] = __hip_atomic_load(q2,   __ATOMIC_RELAXED, __HIP_MEMORY_SCOPE_AGENT);
      f2.u[1] = __hip_atomic_load(q2+1, __ATOMIC_RELAXED, __HIP_MEMORY_SCOPE_AGENT);
      f3.u[0] = __hip_atomic_load(q3,   __ATOMIC_RELAXED, __HIP_MEMORY_SCOPE_AGENT);
      f3.u[1] = __hip_atomic_load(q3+1, __ATOMIC_RELAXED, __HIP_MEMORY_SCOPE_AGENT);
    }

    // ---- own-half GEMM (K = 128, local LDS; no vmem dependency)
    f32x4 a0={0.f,0.f,0.f,0.f}, a1=a0, a2=a0, a3=a0;
    #pragma unroll
    for (int j = 0; j < 4; ++j) {
      f16x8v av = *(const f16x8v*)&hA[cur][(j*64 + lane)*8];
      a0 = MFMA(av, wf[0][j], a0);
      a1 = MFMA(av, wf[1][j], a1);
      a2 = MFMA(av, wf[2][j], a2);
      a3 = MFMA(av, wf[3][j], a3);
    }

    if (t > 0) {
      // ---- 4-way split consume: each check leaves later loads in flight;
      // each 4-MFMA cluster covers the next pair's residual RT.
      while (f0.u[0]==POISON || f0.u[1]==POISON) {
        f0.u[0] = __hip_atomic_load(q0,   __ATOMIC_RELAXED, __HIP_MEMORY_SCOPE_AGENT);
        f0.u[1] = __hip_atomic_load(q0+1, __ATOMIC_RELAXED, __HIP_MEMORY_SCOPE_AGENT);
      }
      __builtin_amdgcn_s_setprio(1);   // data in hand: run ahead of spinners
      a0 = MFMA(f0.v, wf[0][4], a0); a1 = MFMA(f0.v, wf[1][4], a1);
      a2 = MFMA(f0.v, wf[2][4], a2); a3 = MFMA(f0.v, wf[3][4], a3);
      while (f1.u[0]==POISON || f1.u[1]==POISON) {
        f1.u[0] = __hip_atomic_load(q1,   __ATOMIC_RELAXED, __HIP_MEMORY_SCOPE_AGENT);
        f1.u[1] = __hip_atomic_load(q1+1, __ATOMIC_RELAXED, __HIP_MEMORY_SCOPE_AGENT);
      }
      a0 = MFMA(f1.v, wf[0][5], a0); a1 = MFMA(f1.v, wf[1][5], a1);
      a2 = MFMA(f1.v, wf[2][5], a2); a3 = MFMA(f1.v, wf[3][5], a3);
      while (f2.u[0]==POISON || f2.u[1]==POISON) {
        f2.u[0] = __hip_atomic_load(q2,   __ATOMIC_RELAXED, __HIP_MEMORY_SCOPE_AGENT);
        f2.u[1] = __hip_atomic_load(q2+1, __ATOMIC_RELAXED, __HIP_MEMORY_SCOPE_AGENT);
      }
      a0 = MFMA(f2.v, wf[0][6], a0); a1 = MFMA(f2.v, wf[1][6], a1);
      a2 = MFMA(f2.v, wf[2][6], a2); a3 = MFMA(f2.v, wf[3][6], a3);
      while (f3.u[0]==POISON || f3.u[1]==POISON) {
        f3.u[0] = __hip_atomic_load(q3,   __ATOMIC_RELAXED, __HIP_MEMORY_SCOPE_AGENT);
        f3.u[1] = __hip_atomic_load(q3+1, __ATOMIC_RELAXED, __HIP_MEMORY_SCOPE_AGENT);
      }
      a0 = MFMA(f3.v, wf[0][7], a0); a1 = MFMA(f3.v, wf[1][7], a1);
      a2 = MFMA(f3.v, wf[2][7], a2); a3 = MFMA(f3.v, wf[3][7], a3);
    }

    // ---- issue Wx(t+2) prefetch (consumed in 2 steps; never drained early)
    f16x4v xm0,xm1,xm2,xm3;
    if (t < 510) {
      const int pn = dir ? (509 - t) : (t + 2);
      const _Float16* wxp = wxd + (size_t)pn*65536 + woff;
      xm0 = *(const f16x4v*)(wxp + 0*16384);
      xm1 = *(const f16x4v*)(wxp + 1*16384);
      xm2 = *(const f16x4v*)(wxp + 2*16384);
      xm3 = *(const f16x4v*)(wxp + 3*16384);
    }

    // ---- nonlinearity (fused-rcp): lane -> 4 (batch,unit) pairs
    float cc[4] = {c0,c1,c2,c3};
    #pragma unroll
    for (int reg = 0; reg < 4; ++reg) {
      float ai = a0[reg] + (float)xc0[reg];
      float af = a1[reg] + (float)xc1[reg];
      float ag = a2[reg] + (float)xc2[reg];
      float ao = a3[reg] + (float)xc3[reg];
      float eg = __expf(2.f*ag);
      float pi = __expf(-ai);
      float ig = (eg - 1.f) * __builtin_amdgcn_rcpf((1.f + pi)*(eg + 1.f));
      float pf = __expf(-af);
      float c  = __builtin_amdgcn_rcpf(1.f + pf)*cc[reg] + ig;
      cc[reg]  = c;
      float ec = __expf(2.f*c);
      float po = __expf(-ao);
      float hv = (ec - 1.f) * __builtin_amdgcn_rcpf((1.f + po)*(ec + 1.f));
      hA[nb][sbase + reg*8] = (_Float16)hv;
    }
    c0=cc[0]; c1=cc[1]; c2=cc[2]; c3=cc[3];

    // ---- WAVE-LOCAL publish (pre-barrier): my word's 4 f16 were written by
    // lanes of MY wave; in-wave lgkmcnt orders ds_write -> ds_read.
    {
      unsigned long long pw = *(unsigned long long*)&hA[nb][plds];
      __hip_atomic_store(mbu + ((slotb + (size_t)pos*4)<<10) + (half<<9) + pword,
                         pw, __ATOMIC_RELAXED, __HIP_MEMORY_SCOPE_AGENT);
    }
    __builtin_amdgcn_s_setprio(0);

    // ---- RELAXED barrier: order LDS only; publish stores and Wx prefetch
    // stay in flight (never drain vmcnt inside the loop).
    asm volatile("s_waitcnt lgkmcnt(0)\n\ts_barrier" ::: "memory");
    __builtin_amdgcn_sched_barrier(0);

    xc0=xn0; xc1=xn1; xc2=xn2; xc3=xn3;
    if (t < 510) { xn0=xm0; xn1=xm1; xn2=xm2; xn3=xm3; }
  }
}

// ---------------- Phase 3: emission GEMM (K=512, f16 MFMA) + CRF broadcast-add
// v2 (proven round 12): 1024 blocks = (l, batch-half).
__global__ __launch_bounds__(256) void k_out(
    const _Float16* __restrict__ hist, const float* __restrict__ Wlin,
    const float* __restrict__ blin, const float* __restrict__ trans,
    float* __restrict__ out)
{
  __shared__ _Float16 Aa[2*8192];     // 32 KB  [dir][bl 2][4096] A-frags (32 batches)
  __shared__ _Float16 Bf[2*16*64*8];  // 32 KB  W_lin fragments
  __shared__ float    em[32*32];      // 4 KB   emission tile (32 b x 32 out)
  __shared__ float    tt[1024];       // 4 KB   transition
  const int bid = blockIdx.x;         // 0..1023
  const int l   = bid >> 1;
  const int bh  = bid & 1;            // batches bh*32 .. bh*32+31
  const int tid = threadIdx.x;

  for (int d = 0; d < 2; ++d)
    for (int bl = 0; bl < 2; ++bl)
      for (int it = 0; it < 2; ++it) {
        int idx = (it*256 + tid) << 3;   // 0..4095 f16
        *(f16x8v*)&Aa[(d*2 + bl)*4096 + idx] =
            *(const f16x8v*)(hist + (size_t)(d*L_ + l)*16384
                             + (size_t)(bh*2 + bl)*4096 + idx);
      }
  for (int it = 0; it < 8; ++it) {
    int fid = it*256 + tid;
    int lane = fid & 63, ktc = (fid>>6)&15, nt = fid>>10;
    int o = nt*16 + (lane&15), g = lane>>4;
    const float* src = Wlin + (size_t)o*512 + ktc*32 + g*4;
    float4 v1 = *(const float4*)(src);
    float4 v2 = *(const float4*)(src + 16);
    f16x8v p = {(_Float16)v1.x,(_Float16)v1.y,(_Float16)v1.z,(_Float16)v1.w,
                (_Float16)v2.x,(_Float16)v2.y,(_Float16)v2.z,(_Float16)v2.w};
    *(f16x8v*)&Bf[((nt*16+ktc)*64 + lane)<<3] = p;
  }
  *(float4*)&tt[tid*4] = *(const float4*)(trans + tid*4);
  __syncthreads();

  const int w = tid>>6, l64 = tid&63, gq = l64>>4, r = l64&15;
  const int blw = w & 1;              // local bgrp (0/1) -> global bgrp bh*2+blw
  const int nt  = w >> 1;             // out-col tile (0/1)
  {
    f32x4 acc = {0.f,0.f,0.f,0.f};
    for (int ktc = 0; ktc < 16; ++ktc) {
      f16x8v a = *(f16x8v*)&Aa[((ktc>>3)*2 + blw)*4096 + (((ktc&7)*64 + l64)<<3)];
      f16x8v b = *(f16x8v*)&Bf[((nt*16+ktc)*64 + l64)<<3];
      acc = MFMA(a,b,acc);
    }
    float bias = blin[nt*16 + r];
    #pragma unroll
    for (int reg = 0; reg < 4; ++reg)
      em[(blw*16 + gq*4 + reg)*32 + nt*16 + r] = acc[reg] + bias;
  }
  __syncthreads();

  float4 tr4 = *(float4*)&tt[tid*4];                 // trans[i][j0..j0+3], i=tid>>3
  for (int bb = 0; bb < 32; ++bb) {
    int b = bh*32 + bb;
    float4 e4 = *(float4*)&em[bb*32 + (tid&7)*4];    // em[b][j0..j0+3]
    float4 o4 = {e4.x+tr4.x, e4.y+tr4.y, e4.z+tr4.z, e4.w+tr4.w};
    *(float4*)(out + ((size_t)b*512 + l)*1024 + tid*4) = o4;
  }
}

// ---------------- workspace layout (bytes) — identical to round 6 (proven)
//   [0, 134217728)             Wx f16 [2][512][1024][64]
//   [134217728, +33554432)     mailbox/hist f16 [dir2][pos512][bgrp4][4096]
extern "C" void kernel_launch(void* const* d_in, const int* in_sizes, int n_in,
                              void* d_out, int out_size, void* d_ws, size_t ws_size,
                              hipStream_t stream)
{
  (void)in_sizes; (void)n_in; (void)out_size; (void)ws_size;
  const int*   sents = (const int*)  d_in[0];
  const float* emb   = (const float*)d_in[2];
  const float* WihF  = (const float*)d_in[3];
  const float* WhhF  = (const float*)d_in[4];
  const float* bihF  = (const float*)d_in[5];
  const float* bhhF  = (const float*)d_in[6];
  const float* WihB  = (const float*)d_in[7];
  const float* WhhB  = (const float*)d_in[8];
  const float* bihB  = (const float*)d_in[9];
  const float* bhhB  = (const float*)d_in[10];
  const float* Wlin  = (const float*)d_in[11];
  const float* blin  = (const float*)d_in[12];
  const float* trans = (const float*)d_in[13];
  float* out = (float*)d_out;

  char* ws = (char*)d_ws;
  _Float16* wx = (_Float16*)(ws);
  _Float16* mb = (_Float16*)(ws + 134217728);

  hipMemsetAsync(mb, 0xFF, 33554432, stream);   // poison mailbox (data-as-flag)
  hipLaunchKernelGGL(k_wx,   dim3(1024), dim3(256), 0, stream,
                     sents, emb, WihF, WihB, bihF, bhhF, bihB, bhhB, wx);
  hipLaunchKernelGGL(k_scan, dim3(16),   dim3(512), 0, stream,
                     WhhF, WhhB, wx, mb);
  hipLaunchKernelGGL(k_out,  dim3(1024), dim3(256), 0, stream,
                     mb, Wlin, blin, trans, out);
}

// Round 16
// 920.372 us; speedup vs baseline: 1.1317x; 1.1317x over previous
//
#include <hip/hip_runtime.h>
#include <stdint.h>

// Problem constants
#define B_    64
#define L_    512
#define EMB_  128
#define HID_  256
#define OUT_  32

typedef float    f32x4  __attribute__((ext_vector_type(4)));
typedef _Float16 f16x4v __attribute__((ext_vector_type(4)));
typedef _Float16 f16x8v __attribute__((ext_vector_type(8)));

#define MFMA(a,b,c) __builtin_amdgcn_mfma_f32_16x16x32_f16((a),(b),(c),0,0,0)
#define POISON 0xFFFFFFFFFFFFFFFFull

__device__ __forceinline__ f16x4v cvt4(const float4 v){
  f16x4v r = {(_Float16)v.x,(_Float16)v.y,(_Float16)v.z,(_Float16)v.w};
  return r;
}

union u64f16 { unsigned long long u[2]; f16x8v v; };

// MFMA 16x16x32 fragment convention used throughout (lane = 16*g + r):
//   A[16m x 32k]: row = r, k = kt*32 + (j<4 ? 4g+j : 16+4g+(j-4))
//   B[32k x 16n]: col = r, same k mapping
//   D f32x4:      row(m) = 4g+reg, col(n) = r            [m89 HW-verified]

// ---------------- Phase 1: Wx[dir][l][row(1024)][b(64)] f16 = x@Wih^T + bih + bhh
// v2 (proven round 11/12): 1024 blocks; Wih slice staged into LDS ONCE;
// bias hoisted; 8-l loop with two barriers per iteration.
__global__ __launch_bounds__(256) void k_wx(
    const int* __restrict__ sents, const float* __restrict__ emb,
    const float* __restrict__ WihF, const float* __restrict__ WihB,
    const float* __restrict__ bihF, const float* __restrict__ bhhF,
    const float* __restrict__ bihB, const float* __restrict__ bhhB,
    _Float16* __restrict__ wx)
{
  __shared__ _Float16 Af[4*4*64*8];   // 16 KB  x-tile fragments [mt][kt][lane][8]
  __shared__ _Float16 Bf[8*4*64*8];   // 32 KB  Wih fragments [nt][kt][lane][8]
  __shared__ _Float16 Tt[128*64];     // 16 KB  [col][b] out tile
  const int bid = blockIdx.x;         // 0..1023
  const int lb  = (bid >> 4) * 8;     // base l of this block's 8-l chunk
  const int ntb = bid & 15;
  const int dir = ntb >> 3;
  const int tid = threadIdx.x;

  const float* Wih = dir ? WihB : WihF;
  for (int it = 0; it < 16; ++it) {
    int cid = it*256 + tid;               // 4096 = 128 cols * 32 quad-chunks
    int c = cid >> 5, ec = cid & 31, e0 = ec*4;
    int rl = (ntb&7)*128 + c;
    float4 v = *(const float4*)(Wih + (size_t)rl*EMB_ + e0);
    int g = ec & 3, hi = (ec>>2)&1, kt = ec>>3;
    int lane = g*16 + (c&15), nt = c>>4;
    *(f16x4v*)&Bf[(((nt*4+kt)*64 + lane)<<3) + hi*4] = cvt4(v);
  }

  const int w = tid>>6, l64 = tid&63, gq = l64>>4, r = l64&15;
  const float* bih = dir ? bihB : bihF;
  const float* bhh = dir ? bhhB : bhhF;
  float bias8[8];
  #pragma unroll
  for (int nt = 0; nt < 8; ++nt) {
    int rl = (ntb&7)*128 + nt*16 + r;
    bias8[nt] = bih[rl] + bhh[rl];
  }

  for (int li = 0; li < 8; ++li) {
    const int l = lb + li;
    for (int it = 0; it < 8; ++it) {
      int cid = it*256 + tid;             // 2048 = 64 b * 32 quad-chunks
      int b = cid >> 5, ec = cid & 31, e0 = ec*4;
      int tok = sents[b*L_ + l];
      float4 v = *(const float4*)(emb + (size_t)tok*EMB_ + e0);
      int g = ec & 3, hi = (ec>>2)&1, kt = ec>>3;
      int lane = g*16 + (b&15), mt = b>>4;
      *(f16x4v*)&Af[(((mt*4+kt)*64 + lane)<<3) + hi*4] = cvt4(v);
    }
    __syncthreads();                      // Af (and, on li=0, Bf) ready

    #pragma unroll
    for (int nt = 0; nt < 8; ++nt) {
      f32x4 acc = {0.f,0.f,0.f,0.f};
      #pragma unroll
      for (int kt = 0; kt < 4; ++kt) {
        f16x8v a = *(f16x8v*)&Af[((w*4+kt)*64 + l64)<<3];
        f16x8v b = *(f16x8v*)&Bf[((nt*4+kt)*64 + l64)<<3];
        acc = MFMA(a,b,acc);
      }
      int col = nt*16 + r;
      float bias = bias8[nt];
      f16x4v o4 = {(_Float16)(acc[0]+bias),(_Float16)(acc[1]+bias),
                   (_Float16)(acc[2]+bias),(_Float16)(acc[3]+bias)};
      *(f16x4v*)&Tt[col*64 + w*16 + gq*4] = o4;
    }
    __syncthreads();                      // Tt complete; Af reads done

    _Float16* gdst = wx + ((size_t)(dir*L_ + l)*1024 + (size_t)(ntb&7)*128)*64;
    for (int q = 0; q < 4; ++q) {
      int idx = tid*32 + q*8;
      *(f16x8v*)(gdst + idx) = *(f16x8v*)&Tt[idx];
    }
  }
}

// ---------------- Phase 2: LSTM scan (round-12 protocol: per-u64 poison,
// ds_read_b64 wave-local publish, relaxed barrier). 2-WAY SPLIT CONSUME
// (round-14 optimum): check/use f0,f1 first (counted vmcnt leaves q2/q3 in
// flight), run their 8 MFMAs, then check/use f2,f3 — second half's LLC RT
// hides under the first half's MFMAs. 4-way split regressed (round 15):
// finer granularity adds wait points without covering more RT.
__global__ __launch_bounds__(512, 2) void k_scan(
    const float* __restrict__ WhhF, const float* __restrict__ WhhB,
    const _Float16* __restrict__ wx, _Float16* __restrict__ mb)
{
  __shared__ _Float16 hA[2][2048];    // ping-pong OWN-half h A-frags [ktl 4][lane 64][8]
  const int bid  = blockIdx.x;
  const int dir  = bid >> 3;
  const int bgrp = (bid >> 1) & 3;
  const int half = bid & 1;
  const int tid  = threadIdx.x;
  const int w    = tid >> 6;          // wave 0..7 -> unit group ug = half*8+w
  const int lane = tid & 63;
  const int gq   = lane >> 4;
  const int r    = lane & 15;
  const int u    = (half*8 + w)*16 + r;

  // ---- Whh B-fragments into registers (half-relative k): 128 VGPRs
  const float* Whh = dir ? WhhB : WhhF;
  f16x8v wf[4][8];
  #pragma unroll
  for (int nt = 0; nt < 4; ++nt) {
    #pragma unroll
    for (int kk = 0; kk < 8; ++kk) {
      int ktg = (kk < 4) ? (half*4 + kk) : ((half^1)*4 + (kk - 4));
      const float* src = Whh + (size_t)(nt*HID_ + u)*HID_ + ktg*32 + gq*4;
      float4 v1 = *(const float4*)(src);
      float4 v2 = *(const float4*)(src + 16);
      f16x8v p = {(_Float16)v1.x,(_Float16)v1.y,(_Float16)v1.z,(_Float16)v1.w,
                  (_Float16)v2.x,(_Float16)v2.y,(_Float16)v2.z,(_Float16)v2.w};
      wf[nt][kk] = p;
    }
  }

  // ---- zero own-half h0 fragments
  {
    f16x8v z = {(_Float16)0,(_Float16)0,(_Float16)0,(_Float16)0,
                (_Float16)0,(_Float16)0,(_Float16)0,(_Float16)0};
    if (tid < 256) *(f16x8v*)&hA[0][tid*8] = z;
  }

  // ---- Wx addressing: row = g*256 + u, batch offset = bgrp*16 + gq*4
  const _Float16* wxd = wx + (size_t)dir * 33554432ull;   // 512*1024*64
  const size_t woff = (size_t)u*64 + bgrp*16 + gq*4;
  // ---- scatter constants (own new-h into LOCAL A-fragment layout)
  const int ktl   = w >> 1;
  const int sbase = (ktl*64 + (r>>2)*16 + gq*4)*8 + (w&1)*4 + (r&3);
  // ---- publish word: u64 index (own half) whose 4 f16 are written by MY wave
  const int pword = ((w>>1)*64 + lane)*2 + (w&1);   // 0..511
  const int plds  = pword*4;                        // f16 index into hA[nb]
  // ---- mailbox: slot(dir,pos,bgrp) = 1024 u64; own half = 512 u64
  unsigned long long* mbu = (unsigned long long*)mb;
  const size_t slotb = ((size_t)dir*512*4 + bgrp);  // *1024 u64 later
  const int phalf = half ^ 1;

  float c0=0.f, c1=0.f, c2=0.f, c3=0.f;
  f16x4v xc0,xc1,xc2,xc3, xn0,xn1,xn2,xn3;
  {
    const int p0 = dir ? 511 : 0;
    const int p1 = dir ? 510 : 1;
    const _Float16* a = wxd + (size_t)p0*65536 + woff;
    const _Float16* b = wxd + (size_t)p1*65536 + woff;
    xc0 = *(const f16x4v*)(a + 0*16384); xc1 = *(const f16x4v*)(a + 1*16384);
    xc2 = *(const f16x4v*)(a + 2*16384); xc3 = *(const f16x4v*)(a + 3*16384);
    xn0 = *(const f16x4v*)(b + 0*16384); xn1 = *(const f16x4v*)(b + 1*16384);
    xn2 = *(const f16x4v*)(b + 2*16384); xn3 = *(const f16x4v*)(b + 3*16384);
  }
  __syncthreads();

  for (int t = 0; t < L_; ++t) {
    const int cur = t & 1, nb = cur ^ 1;
    const int pos = dir ? (511 - t) : t;

    // ---- issue partner poll loads FIRST (RT overlaps ownGEMM below)
    const int ppos = dir ? (512 - t) : (t - 1);
    const unsigned long long* pb =
        mbu + ((slotb + (size_t)ppos*4)<<10) + (phalf<<9);
    const unsigned long long* q0 = pb + ((0*64 + lane)<<1);
    const unsigned long long* q1 = pb + ((1*64 + lane)<<1);
    const unsigned long long* q2 = pb + ((2*64 + lane)<<1);
    const unsigned long long* q3 = pb + ((3*64 + lane)<<1);
    u64f16 f0, f1, f2, f3;
    if (t > 0) {
      f0.u[0] = __hip_atomic_load(q0,   __ATOMIC_RELAXED, __HIP_MEMORY_SCOPE_AGENT);
      f0.u[1] = __hip_atomic_load(q0+1, __ATOMIC_RELAXED, __HIP_MEMORY_SCOPE_AGENT);
      f1.u[0] = __hip_atomic_load(q1,   __ATOMIC_RELAXED, __HIP_MEMORY_SCOPE_AGENT);
      f1.u[1] = __hip_atomic_load(q1+1, __ATOMIC_RELAXED, __HIP_MEMORY_SCOPE_AGENT);
      f2.u[0] = __hip_atomic_load(q2,   __ATOMIC_RELAXED, __HIP_MEMORY_SCOPE_AGENT);
      f2.u[1] = __hip_atomic_load(q2+1, __ATOMIC_RELAXED, __HIP_MEMORY_SCOPE_AGENT);
      f3.u[0] = __hip_atomic_load(q3,   __ATOMIC_RELAXED, __HIP_MEMORY_SCOPE_AGENT);
      f3.u[1] = __hip_atomic_load(q3+1, __ATOMIC_RELAXED, __HIP_MEMORY_SCOPE_AGENT);
    }

    // ---- own-half GEMM (K = 128, local LDS; no vmem dependency)
    f32x4 a0={0.f,0.f,0.f,0.f}, a1=a0, a2=a0, a3=a0;
    #pragma unroll
    for (int j = 0; j < 4; ++j) {
      f16x8v av = *(const f16x8v*)&hA[cur][(j*64 + lane)*8];
      a0 = MFMA(av, wf[0][j], a0);
      a1 = MFMA(av, wf[1][j], a1);
      a2 = MFMA(av, wf[2][j], a2);
      a3 = MFMA(av, wf[3][j], a3);
    }

    if (t > 0) {
      // ---- first half: check/retry f0,f1 only (q2/q3 stay in flight)
      while (f0.u[0]==POISON || f0.u[1]==POISON ||
             f1.u[0]==POISON || f1.u[1]==POISON) {
        f0.u[0] = __hip_atomic_load(q0,   __ATOMIC_RELAXED, __HIP_MEMORY_SCOPE_AGENT);
        f0.u[1] = __hip_atomic_load(q0+1, __ATOMIC_RELAXED, __HIP_MEMORY_SCOPE_AGENT);
        f1.u[0] = __hip_atomic_load(q1,   __ATOMIC_RELAXED, __HIP_MEMORY_SCOPE_AGENT);
        f1.u[1] = __hip_atomic_load(q1+1, __ATOMIC_RELAXED, __HIP_MEMORY_SCOPE_AGENT);
      }
      __builtin_amdgcn_s_setprio(1);   // data in hand: run ahead of spinners
      a0 = MFMA(f0.v, wf[0][4], a0); a1 = MFMA(f0.v, wf[1][4], a1);
      a2 = MFMA(f0.v, wf[2][4], a2); a3 = MFMA(f0.v, wf[3][4], a3);
      a0 = MFMA(f1.v, wf[0][5], a0); a1 = MFMA(f1.v, wf[1][5], a1);
      a2 = MFMA(f1.v, wf[2][5], a2); a3 = MFMA(f1.v, wf[3][5], a3);
      // ---- second half: RT hidden under the 8 MFMAs above
      while (f2.u[0]==POISON || f2.u[1]==POISON ||
             f3.u[0]==POISON || f3.u[1]==POISON) {
        f2.u[0] = __hip_atomic_load(q2,   __ATOMIC_RELAXED, __HIP_MEMORY_SCOPE_AGENT);
        f2.u[1] = __hip_atomic_load(q2+1, __ATOMIC_RELAXED, __HIP_MEMORY_SCOPE_AGENT);
        f3.u[0] = __hip_atomic_load(q3,   __ATOMIC_RELAXED, __HIP_MEMORY_SCOPE_AGENT);
        f3.u[1] = __hip_atomic_load(q3+1, __ATOMIC_RELAXED, __HIP_MEMORY_SCOPE_AGENT);
      }
      a0 = MFMA(f2.v, wf[0][6], a0); a1 = MFMA(f2.v, wf[1][6], a1);
      a2 = MFMA(f2.v, wf[2][6], a2); a3 = MFMA(f2.v, wf[3][6], a3);
      a0 = MFMA(f3.v, wf[0][7], a0); a1 = MFMA(f3.v, wf[1][7], a1);
      a2 = MFMA(f3.v, wf[2][7], a2); a3 = MFMA(f3.v, wf[3][7], a3);
    }

    // ---- issue Wx(t+2) prefetch (consumed in 2 steps; never drained early)
    f16x4v xm0,xm1,xm2,xm3;
    if (t < 510) {
      const int pn = dir ? (509 - t) : (t + 2);
      const _Float16* wxp = wxd + (size_t)pn*65536 + woff;
      xm0 = *(const f16x4v*)(wxp + 0*16384);
      xm1 = *(const f16x4v*)(wxp + 1*16384);
      xm2 = *(const f16x4v*)(wxp + 2*16384);
      xm3 = *(const f16x4v*)(wxp + 3*16384);
    }

    // ---- nonlinearity (fused-rcp): lane -> 4 (batch,unit) pairs
    float cc[4] = {c0,c1,c2,c3};
    #pragma unroll
    for (int reg = 0; reg < 4; ++reg) {
      float ai = a0[reg] + (float)xc0[reg];
      float af = a1[reg] + (float)xc1[reg];
      float ag = a2[reg] + (float)xc2[reg];
      float ao = a3[reg] + (float)xc3[reg];
      float eg = __expf(2.f*ag);
      float pi = __expf(-ai);
      float ig = (eg - 1.f) * __builtin_amdgcn_rcpf((1.f + pi)*(eg + 1.f));
      float pf = __expf(-af);
      float c  = __builtin_amdgcn_rcpf(1.f + pf)*cc[reg] + ig;
      cc[reg]  = c;
      float ec = __expf(2.f*c);
      float po = __expf(-ao);
      float hv = (ec - 1.f) * __builtin_amdgcn_rcpf((1.f + po)*(ec + 1.f));
      hA[nb][sbase + reg*8] = (_Float16)hv;
    }
    c0=cc[0]; c1=cc[1]; c2=cc[2]; c3=cc[3];

    // ---- WAVE-LOCAL publish (pre-barrier): my word's 4 f16 were written by
    // lanes of MY wave; in-wave lgkmcnt orders ds_write -> ds_read.
    {
      unsigned long long pw = *(unsigned long long*)&hA[nb][plds];
      __hip_atomic_store(mbu + ((slotb + (size_t)pos*4)<<10) + (half<<9) + pword,
                         pw, __ATOMIC_RELAXED, __HIP_MEMORY_SCOPE_AGENT);
    }
    __builtin_amdgcn_s_setprio(0);

    // ---- RELAXED barrier: order LDS only; publish stores and Wx prefetch
    // stay in flight (never drain vmcnt inside the loop).
    asm volatile("s_waitcnt lgkmcnt(0)\n\ts_barrier" ::: "memory");
    __builtin_amdgcn_sched_barrier(0);

    xc0=xn0; xc1=xn1; xc2=xn2; xc3=xn3;
    if (t < 510) { xn0=xm0; xn1=xm1; xn2=xm2; xn3=xm3; }
  }
}

// ---------------- Phase 3: emission GEMM (K=512, f16 MFMA) + CRF broadcast-add
// v2 (proven round 12): 1024 blocks = (l, batch-half).
__global__ __launch_bounds__(256) void k_out(
    const _Float16* __restrict__ hist, const float* __restrict__ Wlin,
    const float* __restrict__ blin, const float* __restrict__ trans,
    float* __restrict__ out)
{
  __shared__ _Float16 Aa[2*8192];     // 32 KB  [dir][bl 2][4096] A-frags (32 batches)
  __shared__ _Float16 Bf[2*16*64*8];  // 32 KB  W_lin fragments
  __shared__ float    em[32*32];      // 4 KB   emission tile (32 b x 32 out)
  __shared__ float    tt[1024];       // 4 KB   transition
  const int bid = blockIdx.x;         // 0..1023
  const int l   = bid >> 1;
  const int bh  = bid & 1;            // batches bh*32 .. bh*32+31
  const int tid = threadIdx.x;

  for (int d = 0; d < 2; ++d)
    for (int bl = 0; bl < 2; ++bl)
      for (int it = 0; it < 2; ++it) {
        int idx = (it*256 + tid) << 3;   // 0..4095 f16
        *(f16x8v*)&Aa[(d*2 + bl)*4096 + idx] =
            *(const f16x8v*)(hist + (size_t)(d*L_ + l)*16384
                             + (size_t)(bh*2 + bl)*4096 + idx);
      }
  for (int it = 0; it < 8; ++it) {
    int fid = it*256 + tid;
    int lane = fid & 63, ktc = (fid>>6)&15, nt = fid>>10;
    int o = nt*16 + (lane&15), g = lane>>4;
    const float* src = Wlin + (size_t)o*512 + ktc*32 + g*4;
    float4 v1 = *(const float4*)(src);
    float4 v2 = *(const float4*)(src + 16);
    f16x8v p = {(_Float16)v1.x,(_Float16)v1.y,(_Float16)v1.z,(_Float16)v1.w,
                (_Float16)v2.x,(_Float16)v2.y,(_Float16)v2.z,(_Float16)v2.w};
    *(f16x8v*)&Bf[((nt*16+ktc)*64 + lane)<<3] = p;
  }
  *(float4*)&tt[tid*4] = *(const float4*)(trans + tid*4);
  __syncthreads();

  const int w = tid>>6, l64 = tid&63, gq = l64>>4, r = l64&15;
  const int blw = w & 1;              // local bgrp (0/1) -> global bgrp bh*2+blw
  const int nt  = w >> 1;             // out-col tile (0/1)
  {
    f32x4 acc = {0.f,0.f,0.f,0.f};
    for (int ktc = 0; ktc < 16; ++ktc) {
      f16x8v a = *(f16x8v*)&Aa[((ktc>>3)*2 + blw)*4096 + (((ktc&7)*64 + l64)<<3)];
      f16x8v b = *(f16x8v*)&Bf[((nt*16+ktc)*64 + l64)<<3];
      acc = MFMA(a,b,acc);
    }
    float bias = blin[nt*16 + r];
    #pragma unroll
    for (int reg = 0; reg < 4; ++reg)
      em[(blw*16 + gq*4 + reg)*32 + nt*16 + r] = acc[reg] + bias;
  }
  __syncthreads();

  float4 tr4 = *(float4*)&tt[tid*4];                 // trans[i][j0..j0+3], i=tid>>3
  for (int bb = 0; bb < 32; ++bb) {
    int b = bh*32 + bb;
    float4 e4 = *(float4*)&em[bb*32 + (tid&7)*4];    // em[b][j0..j0+3]
    float4 o4 = {e4.x+tr4.x, e4.y+tr4.y, e4.z+tr4.z, e4.w+tr4.w};
    *(float4*)(out + ((size_t)b*512 + l)*1024 + tid*4) = o4;
  }
}

// ---------------- workspace layout (bytes) — identical to round 6 (proven)
//   [0, 134217728)             Wx f16 [2][512][1024][64]
//   [134217728, +33554432)     mailbox/hist f16 [dir2][pos512][bgrp4][4096]
extern "C" void kernel_launch(void* const* d_in, const int* in_sizes, int n_in,
                              void* d_out, int out_size, void* d_ws, size_t ws_size,
                              hipStream_t stream)
{
  (void)in_sizes; (void)n_in; (void)out_size; (void)ws_size;
  const int*   sents = (const int*)  d_in[0];
  const float* emb   = (const float*)d_in[2];
  const float* WihF  = (const float*)d_in[3];
  const float* WhhF  = (const float*)d_in[4];
  const float* bihF  = (const float*)d_in[5];
  const float* bhhF  = (const float*)d_in[6];
  const float* WihB  = (const float*)d_in[7];
  const float* WhhB  = (const float*)d_in[8];
  const float* bihB  = (const float*)d_in[9];
  const float* bhhB  = (const float*)d_in[10];
  const float* Wlin  = (const float*)d_in[11];
  const float* blin  = (const float*)d_in[12];
  const float* trans = (const float*)d_in[13];
  float* out = (float*)d_out;

  char* ws = (char*)d_ws;
  _Float16* wx = (_Float16*)(ws);
  _Float16* mb = (_Float16*)(ws + 134217728);

  hipMemsetAsync(mb, 0xFF, 33554432, stream);   // poison mailbox (data-as-flag)
  hipLaunchKernelGGL(k_wx,   dim3(1024), dim3(256), 0, stream,
                     sents, emb, WihF, WihB, bihF, bhhF, bihB, bhhB, wx);
  hipLaunchKernelGGL(k_scan, dim3(16),   dim3(512), 0, stream,
                     WhhF, WhhB, wx, mb);
  hipLaunchKernelGGL(k_out,  dim3(1024), dim3(256), 0, stream,
                     mb, Wlin, blin, trans, out);
}